// Round 7
// baseline (197.879 us; speedup 1.0000x reference)
//
#include <hip/hip_runtime.h>
#include <hip/hip_bf16.h>

#define K_DIM 4096
#define N_DIM 11008
#define REP 4   // DIAGNOSTIC: repeat compute to surface gemm counters above the
                // harness's ~40us poison-fill dispatches in the top-5 table.

typedef __attribute__((ext_vector_type(4))) float f32x4;
typedef _Float16 half8 __attribute__((ext_vector_type(8)));
typedef _Float16 half2v __attribute__((ext_vector_type(2)));
typedef unsigned int uint32;

// ---------------- prep: x[64,4096] f32 -> xp f16, fragment-major, AWQ-permuted
// (unchanged from rounds 3-6; mapping validated by passing correctness)
__global__ __launch_bounds__(256) void prep_x(const float* __restrict__ x,
                                              unsigned short* __restrict__ xp) {
    const int g = blockIdx.x * 256 + threadIdx.x;      // 0..32767
    const int lane = g & 63, mt = (g >> 6) & 3, h = (g >> 8) & 1, kg = g >> 9;
    const int m = mt * 16 + (lane & 15), qq = lane >> 4;
    union { unsigned short v[8]; uint4 u4; } r;
#pragma unroll
    for (int e = 0; e < 8; ++e) {
        const int kp = h * 32 + qq * 8 + e;
        const int t = kp >> 2, ip = kp & 3;
        const int i = ((ip & 1) << 1) | (ip >> 1);
        const int col = ((t >> 3) << 5) + (t & 7) + (i << 3);
        const _Float16 hf = (_Float16)x[m * K_DIM + kg * 64 + col];
        r.v[e] = __builtin_bit_cast(unsigned short, hf);
    }
    *(uint4*)(xp + (size_t)g * 8) = r.u4;
}

// ---------------- dequant 2 packed words -> one B-fragment (8 f16, k'-ordered)
__device__ __forceinline__ half8 build_bfrag(int w0, int w1, half2v s2, half2v c2) {
    union { half8 h; half2v p[4]; } r;
    const half2v k1024 = {(_Float16)1024.0f, (_Float16)1024.0f};
    const uint32 u0 = (uint32)(w0 & 0xF)        | (((uint32)w0 & 0xF00u) << 8) | 0x64006400u;
    const uint32 u1 = (uint32)((w0 >> 4) & 0xF) | (((uint32)w0 & 0xF000u) << 4) | 0x64006400u;
    const uint32 u2 = (uint32)(w1 & 0xF)        | (((uint32)w1 & 0xF00u) << 8) | 0x64006400u;
    const uint32 u3 = (uint32)((w1 >> 4) & 0xF) | (((uint32)w1 & 0xF000u) << 4) | 0x64006400u;
    half2v q;
    q = __builtin_bit_cast(half2v, u0) - k1024; r.p[0] = q * s2 + c2;
    q = __builtin_bit_cast(half2v, u1) - k1024; r.p[1] = q * s2 + c2;
    q = __builtin_bit_cast(half2v, u2) - k1024; r.p[2] = q * s2 + c2;
    q = __builtin_bit_cast(half2v, u3) - k1024; r.p[3] = q * s2 + c2;
    return r.h;
}

// ---------------- main GEMM: r6 structure exactly, plus REP diagnostic loop.
// acc accumulates REP identical passes; final acc *= 1/REP (exact pow2 scale).
__global__ __launch_bounds__(256, 5) void w4_gemm(
    const unsigned short* __restrict__ xp,
    const int*   __restrict__ qw,
    const float* __restrict__ scale,
    const float* __restrict__ zp,
    f32x4*       __restrict__ ws)
{
    __shared__ f32x4 part[1024];             // 16 KB

    const int tid = threadIdx.x, lane = tid & 63, j = tid >> 6;
    const int nl = lane & 15, q = lane >> 4;
    const int nx = blockIdx.x, ky = blockIdx.y;
    const int n0 = nx * 32;
    const int nnA = n0 + nl, nnB = n0 + 16 + nl;

    const float sA = scale[nnA], zA = zp[nnA];
    const float sB = scale[nnB], zB = zp[nnB];
    const _Float16 shA = (_Float16)sA, chA = (_Float16)(-zA * sA);
    const _Float16 shB = (_Float16)sB, chB = (_Float16)(-zB * sB);
    const half2v s2A = {shA, shA}, c2A = {chA, chA};
    const half2v s2B = {shB, shB}, c2B = {chB, chB};

    const int* qbA = qw + ((size_t)(nnA >> 2) * K_DIM) + ((nnA & 3) * 16) + 2 * q;
    const int* qbB = qw + ((size_t)(nnB >> 2) * K_DIM) + ((nnB & 3) * 16) + 2 * q;

    const int kg0 = ky * 16 + j * 4;

    int2 qa[2][2][2];                        // [buf][tile][h]
    auto loadq = [&](int buf, int kg) {
        const int off = kg * 64;
        qa[buf][0][0] = *(const int2*)(qbA + off);
        qa[buf][0][1] = *(const int2*)(qbA + off + 8);
        qa[buf][1][0] = *(const int2*)(qbB + off);
        qa[buf][1][1] = *(const int2*)(qbB + off + 8);
    };

    f32x4 acc[2][4] = {};                    // [tile][mt]

#pragma unroll 1
    for (int rep = 0; rep < REP; ++rep) {
        loadq(0, kg0);
#pragma unroll
        for (int it = 0; it < 4; ++it) {
            if (it < 3) loadq((it + 1) & 1, kg0 + it + 1);
            const int b = it & 1;
            const unsigned short* ab = xp + (size_t)(kg0 + it) * 4096;
#pragma unroll
            for (int h = 0; h < 2; ++h) {
                const half8 bfA = build_bfrag(qa[b][0][h].x, qa[b][0][h].y, s2A, c2A);
                const half8 bfB = build_bfrag(qa[b][1][h].x, qa[b][1][h].y, s2B, c2B);
#pragma unroll
                for (int mt = 0; mt < 4; ++mt) {
                    const half8 af = *(const half8*)(ab + (h * 4 + mt) * 512 + lane * 8);
                    acc[0][mt] = __builtin_amdgcn_mfma_f32_16x16x32_f16(af, bfA, acc[0][mt], 0, 0, 0);
                    acc[1][mt] = __builtin_amdgcn_mfma_f32_16x16x32_f16(af, bfB, acc[1][mt], 0, 0, 0);
                }
            }
        }
    }

    // undo the REP-fold accumulation (exact: power-of-2 scale)
    const float inv = 1.0f / (float)REP;
#pragma unroll
    for (int nt = 0; nt < 2; ++nt)
#pragma unroll
        for (int mt = 0; mt < 4; ++mt)
            acc[nt][mt] *= inv;

    // two-phase 16 KB LDS reduce over j (r6 verbatim)
    f32x4* wsb = ws + ((size_t)nx * 4 + ky) * 512;
#pragma unroll
    for (int p = 0; p < 2; ++p) {
#pragma unroll
        for (int mt = 0; mt < 4; ++mt)
            part[j * 256 + mt * 64 + q * 16 + nl] = acc[p][mt];
        __syncthreads();
        {
            f32x4 v = part[tid];
            v += part[256 + tid];
            v += part[512 + tid];
            v += part[768 + tid];
            wsb[p * 256 + tid] = v;
        }
        if (p == 0) __syncthreads();
    }
}

// ---------------- final reduce (r6 verbatim)
__global__ __launch_bounds__(256) void reduce_k(
    const f32x4* __restrict__ ws,
    const float* __restrict__ bias,
    float*       __restrict__ out)
{
    const int nx = blockIdx.x, tid = threadIdx.x;
    const f32x4* wsb = ws + (size_t)nx * 4 * 512;
#pragma unroll
    for (int ss = 0; ss < 2; ++ss) {
        const int s = tid + ss * 256;
        f32x4 v = wsb[s];
        v += wsb[512 + s];
        v += wsb[1024 + s];
        v += wsb[1536 + s];
        const int nt = s >> 8, mt = (s >> 6) & 3, qq = (s >> 4) & 3, nl = s & 15;
        const int n = nx * 32 + nt * 16 + nl;
        const float bv = bias[n];
        const int m0 = mt * 16 + qq * 4;
#pragma unroll
        for (int r = 0; r < 4; ++r)
            out[(size_t)(m0 + r) * N_DIM + n] = v[r] + bv;
    }
}

extern "C" void kernel_launch(void* const* d_in, const int* in_sizes, int n_in,
                              void* d_out, int out_size, void* d_ws, size_t ws_size,
                              hipStream_t stream) {
    const float* x     = (const float*)d_in[0];
    const int*   qw    = (const int*)d_in[1];
    const float* scale = (const float*)d_in[2];
    const float* zp    = (const float*)d_in[3];
    const float* bias  = (const float*)d_in[4];
    float* out = (float*)d_out;

    unsigned short* xp = (unsigned short*)d_ws;                  // 512 KB
    f32x4* part_ws = (f32x4*)((char*)d_ws + (1 << 20));          // 11.3 MB partials

    prep_x<<<128, 256, 0, stream>>>(x, xp);
    dim3 grid(344, 4);
    w4_gemm<<<grid, 256, 0, stream>>>(xp, qw, scale, zp, part_ws);
    reduce_k<<<344, 256, 0, stream>>>(part_ws, bias, out);
}

// Round 9
// 34.998 us; speedup vs baseline: 5.6541x; 5.6541x over previous
//
#include <hip/hip_runtime.h>
#include <hip/hip_bf16.h>

#define K_DIM 4096
#define N_DIM 11008

typedef __attribute__((ext_vector_type(4))) float f32x4;
typedef _Float16 half8 __attribute__((ext_vector_type(8)));
typedef _Float16 half2v __attribute__((ext_vector_type(2)));
typedef int int2v __attribute__((ext_vector_type(2)));   // native vec for nt-load
typedef unsigned int uint32;

// ---------------- prep: x[64,4096] f32 -> xp f16, fragment-major, AWQ-permuted
// xp slot (kg, h, mt): halfword offset (kg*8 + h*4 + mt)*512 + lane*8.
// Lane element e: m = mt*16+(lane&15); k' = h*32+(lane>>4)*8+e;
//   t = k'>>2, i' = k'&3, i = ((i'&1)<<1)|(i'>>1); col = (t>=8?32:0)+(t&7)+8i
// (mapping validated: rounds 1-7 pass correctness)
__global__ __launch_bounds__(256) void prep_x(const float* __restrict__ x,
                                              unsigned short* __restrict__ xp) {
    const int g = blockIdx.x * 256 + threadIdx.x;      // 0..32767
    const int lane = g & 63, mt = (g >> 6) & 3, h = (g >> 8) & 1, kg = g >> 9;
    const int m = mt * 16 + (lane & 15), qq = lane >> 4;
    union { unsigned short v[8]; uint4 u4; } r;
#pragma unroll
    for (int e = 0; e < 8; ++e) {
        const int kp = h * 32 + qq * 8 + e;
        const int t = kp >> 2, ip = kp & 3;
        const int i = ((ip & 1) << 1) | (ip >> 1);
        const int col = ((t >> 3) << 5) + (t & 7) + (i << 3);
        const _Float16 hf = (_Float16)x[m * K_DIM + kg * 64 + col];
        r.v[e] = __builtin_bit_cast(unsigned short, hf);
    }
    *(uint4*)(xp + (size_t)g * 8) = r.u4;
}

// ---------------- dequant 2 packed words -> one B-fragment (8 f16, k'-ordered)
__device__ __forceinline__ half8 build_bfrag(int w0, int w1, half2v s2, half2v c2) {
    union { half8 h; half2v p[4]; } r;
    const half2v k1024 = {(_Float16)1024.0f, (_Float16)1024.0f};
    const uint32 u0 = (uint32)(w0 & 0xF)        | (((uint32)w0 & 0xF00u) << 8) | 0x64006400u;
    const uint32 u1 = (uint32)((w0 >> 4) & 0xF) | (((uint32)w0 & 0xF000u) << 4) | 0x64006400u;
    const uint32 u2 = (uint32)(w1 & 0xF)        | (((uint32)w1 & 0xF00u) << 8) | 0x64006400u;
    const uint32 u3 = (uint32)((w1 >> 4) & 0xF) | (((uint32)w1 & 0xF000u) << 4) | 0x64006400u;
    half2v q;
    q = __builtin_bit_cast(half2v, u0) - k1024; r.p[0] = q * s2 + c2;
    q = __builtin_bit_cast(half2v, u1) - k1024; r.p[1] = q * s2 + c2;
    q = __builtin_bit_cast(half2v, u2) - k1024; r.p[2] = q * s2 + c2;
    q = __builtin_bit_cast(half2v, u3) - k1024; r.p[3] = q * s2 + c2;
    return r.h;
}

// ---------------- main GEMM: grid (344, 4), 256 thr (4 waves) — r5 structure.
// Wave (nx, ky, j): 64m x 32n tile, kg in [ky*16 + j*4, +4).
// NEW vs r5: qw stream loaded NON-TEMPORALLY (no L2 allocation) so the 45 MB
// weight stream stops thrashing the 4 MB per-XCD L2 and xp A-fragments stay
// L2-resident (theory: af L2-misses were the stall chain; r7 FETCH showed
// ~200 MB of xp miss traffic).
__global__ __launch_bounds__(256) void w4_gemm(
    const unsigned short* __restrict__ xp,   // f16, fragment-major
    const int*   __restrict__ qw,            // [2752, 4096] packed
    const float* __restrict__ scale,
    const float* __restrict__ zp,
    f32x4*       __restrict__ ws)            // partials [344*4][512] f32x4
{
    __shared__ f32x4 part[2048];             // 32 KB

    const int tid = threadIdx.x, lane = tid & 63, j = tid >> 6;
    const int nl = lane & 15, q = lane >> 4;
    const int nx = blockIdx.x, ky = blockIdx.y;
    const int n0 = nx * 32;
    const int nnA = n0 + nl, nnB = n0 + 16 + nl;

    const float sA = scale[nnA], zA = zp[nnA];
    const float sB = scale[nnB], zB = zp[nnB];
    const _Float16 shA = (_Float16)sA, chA = (_Float16)(-zA * sA);
    const _Float16 shB = (_Float16)sB, chB = (_Float16)(-zB * sB);
    const half2v s2A = {shA, shA}, c2A = {chA, chA};
    const half2v s2B = {shB, shB}, c2B = {chB, chB};

    const int* qbA = qw + ((size_t)(nnA >> 2) * K_DIM) + ((nnA & 3) * 16) + 2 * q;
    const int* qbB = qw + ((size_t)(nnB >> 2) * K_DIM) + ((nnB & 3) * 16) + 2 * q;

    const int kg0 = ky * 16 + j * 4;

    // ---- issue ALL qw loads for this wave's slice upfront (16 independent),
    // non-temporal: stream past L2.
    int2v qa[4][2][2];                       // [it][tile][h] — static idx (unrolled)
#pragma unroll
    for (int it = 0; it < 4; ++it) {
        const int off = (kg0 + it) * 64;
        qa[it][0][0] = __builtin_nontemporal_load((const int2v*)(qbA + off));
        qa[it][0][1] = __builtin_nontemporal_load((const int2v*)(qbA + off + 8));
        qa[it][1][0] = __builtin_nontemporal_load((const int2v*)(qbB + off));
        qa[it][1][1] = __builtin_nontemporal_load((const int2v*)(qbB + off + 8));
    }

    f32x4 acc[2][4] = {};                    // [tile][mt]
#pragma unroll
    for (int it = 0; it < 4; ++it) {
        const unsigned short* ab = xp + (size_t)(kg0 + it) * 4096;
#pragma unroll
        for (int h = 0; h < 2; ++h) {
            const half8 bfA = build_bfrag(qa[it][0][h].x, qa[it][0][h].y, s2A, c2A);
            const half8 bfB = build_bfrag(qa[it][1][h].x, qa[it][1][h].y, s2B, c2B);
#pragma unroll
            for (int mt = 0; mt < 4; ++mt) {
                const half8 af = *(const half8*)(ab + (h * 4 + mt) * 512 + lane * 8);
                acc[0][mt] = __builtin_amdgcn_mfma_f32_16x16x32_f16(af, bfA, acc[0][mt], 0, 0, 0);
                acc[1][mt] = __builtin_amdgcn_mfma_f32_16x16x32_f16(af, bfB, acc[1][mt], 0, 0, 0);
            }
        }
    }

    // partials: part[((j*2+nt)*4+mt)*64 + q*16 + nl]  (r5 verbatim)
#pragma unroll
    for (int nt = 0; nt < 2; ++nt)
#pragma unroll
        for (int mt = 0; mt < 4; ++mt)
            part[((j * 2 + nt) * 4 + mt) * 64 + q * 16 + nl] = acc[nt][mt];
    __syncthreads();

    f32x4* wsb = ws + ((size_t)nx * 4 + ky) * 512;
#pragma unroll
    for (int ss = 0; ss < 2; ++ss) {
        const int s = tid + ss * 256;
        f32x4 v = part[s];
        v += part[512 + s];
        v += part[1024 + s];
        v += part[1536 + s];
        wsb[s] = v;
    }
}

// ---------------- final reduce: sum 4 ky partials + bias -> out (r5 verbatim)
__global__ __launch_bounds__(256) void reduce_k(
    const f32x4* __restrict__ ws,
    const float* __restrict__ bias,
    float*       __restrict__ out)
{
    const int nx = blockIdx.x, tid = threadIdx.x;
    const f32x4* wsb = ws + (size_t)nx * 4 * 512;
#pragma unroll
    for (int ss = 0; ss < 2; ++ss) {
        const int s = tid + ss * 256;
        f32x4 v = wsb[s];
        v += wsb[512 + s];
        v += wsb[1024 + s];
        v += wsb[1536 + s];
        const int nt = s >> 8, mt = (s >> 6) & 3, qq = (s >> 4) & 3, nl = s & 15;
        const int n = nx * 32 + nt * 16 + nl;
        const float bv = bias[n];
        const int m0 = mt * 16 + qq * 4;
#pragma unroll
        for (int r = 0; r < 4; ++r)
            out[(size_t)(m0 + r) * N_DIM + n] = v[r] + bv;
    }
}

extern "C" void kernel_launch(void* const* d_in, const int* in_sizes, int n_in,
                              void* d_out, int out_size, void* d_ws, size_t ws_size,
                              hipStream_t stream) {
    const float* x     = (const float*)d_in[0];
    const int*   qw    = (const int*)d_in[1];
    const float* scale = (const float*)d_in[2];
    const float* zp    = (const float*)d_in[3];
    const float* bias  = (const float*)d_in[4];
    float* out = (float*)d_out;

    unsigned short* xp = (unsigned short*)d_ws;                  // 512 KB
    f32x4* part_ws = (f32x4*)((char*)d_ws + (1 << 20));          // 5.6 MB partials

    prep_x<<<128, 256, 0, stream>>>(x, xp);
    dim3 grid(344, 4);
    w4_gemm<<<grid, 256, 0, stream>>>(xp, qw, scale, zp, part_ws);
    reduce_k<<<344, 256, 0, stream>>>(part_ws, bias, out);
}

// Round 13
// 29.914 us; speedup vs baseline: 6.6148x; 1.1699x over previous
//
#include <hip/hip_runtime.h>
#include <hip/hip_bf16.h>

#define K_DIM 4096
#define N_DIM 11008

typedef __attribute__((ext_vector_type(4))) float f32x4;
typedef _Float16 half8 __attribute__((ext_vector_type(8)));
typedef _Float16 half2v __attribute__((ext_vector_type(2)));
typedef int int2v __attribute__((ext_vector_type(2)));
typedef unsigned int uint32;
typedef __attribute__((address_space(1))) const char gchar_t;   // global AS
typedef __attribute__((address_space(3))) char lchar_t;         // LDS AS

// ---------------- prep: x[64,4096] f32 -> xp f16, fragment-major, AWQ-permuted
// xp byte layout: kg-block (8192 B) = [(h*4+mt)*1024 + lane*16], lane elem e:
//   m = mt*16+(lane&15); k' = h*32+(lane>>4)*8+e;
//   t = k'>>2, i' = k'&3, i = ((i'&1)<<1)|(i'>>1); col = (t>=8?32:0)+(t&7)+8i
// (mapping validated: rounds 1-9 pass correctness)
__global__ __launch_bounds__(256) void prep_x(const float* __restrict__ x,
                                              unsigned short* __restrict__ xp) {
    const int g = blockIdx.x * 256 + threadIdx.x;      // 0..32767
    const int lane = g & 63, mt = (g >> 6) & 3, h = (g >> 8) & 1, kg = g >> 9;
    const int m = mt * 16 + (lane & 15), qq = lane >> 4;
    union { unsigned short v[8]; uint4 u4; } r;
#pragma unroll
    for (int e = 0; e < 8; ++e) {
        const int kp = h * 32 + qq * 8 + e;
        const int t = kp >> 2, ip = kp & 3;
        const int i = ((ip & 1) << 1) | (ip >> 1);
        const int col = ((t >> 3) << 5) + (t & 7) + (i << 3);
        const _Float16 hf = (_Float16)x[m * K_DIM + kg * 64 + col];
        r.v[e] = __builtin_bit_cast(unsigned short, hf);
    }
    *(uint4*)(xp + (size_t)g * 8) = r.u4;
}

// ---------------- dequant 2 packed words -> one B-fragment (8 f16, k'-ordered)
__device__ __forceinline__ half8 build_bfrag(int w0, int w1, half2v s2, half2v c2) {
    union { half8 h; half2v p[4]; } r;
    const half2v k1024 = {(_Float16)1024.0f, (_Float16)1024.0f};
    const uint32 u0 = (uint32)(w0 & 0xF)        | (((uint32)w0 & 0xF00u) << 8) | 0x64006400u;
    const uint32 u1 = (uint32)((w0 >> 4) & 0xF) | (((uint32)w0 & 0xF000u) << 4) | 0x64006400u;
    const uint32 u2 = (uint32)(w1 & 0xF)        | (((uint32)w1 & 0xF00u) << 8) | 0x64006400u;
    const uint32 u3 = (uint32)((w1 >> 4) & 0xF) | (((uint32)w1 & 0xF000u) << 4) | 0x64006400u;
    half2v q;
    q = __builtin_bit_cast(half2v, u0) - k1024; r.p[0] = q * s2 + c2;
    q = __builtin_bit_cast(half2v, u1) - k1024; r.p[1] = q * s2 + c2;
    q = __builtin_bit_cast(half2v, u2) - k1024; r.p[2] = q * s2 + c2;
    q = __builtin_bit_cast(half2v, u3) - k1024; r.p[3] = q * s2 + c2;
    return r.h;
}

// ---------------- main GEMM: grid (172, 8), 256 thr (4 waves).
// WG tile 64m x 64n, K-chunk 512 (8 kg steps). Wave w owns n-subtile w.
// A: global_load_lds DMA (contiguous source — m97-verified mechanism),
//    2-slot double buffer in 16 KB LDS.
// B: register 2-deep prefetch (r5/r6-verified mechanism).
// Sync: explicit s_waitcnt vmcnt(0) lgkmcnt(0) + s_barrier + sched_barrier(0)
// per step — drain forced, not assumed (r10-r12 races came from assumed
// drains). Loop fully unrolled so all qa/slot indices are compile-time.
__global__ __launch_bounds__(256) void w4_gemm(
    const unsigned short* __restrict__ xp,   // f16, fragment-major, 512 KB
    const int*   __restrict__ qw,            // [2752, 4096] packed
    const float* __restrict__ scale,
    const float* __restrict__ zp,
    f32x4*       __restrict__ ws)            // partials [172*8][1024] f32x4
{
    __shared__ alignas(16) char lds[2 * 8192];    // 2 slots x 8 KB (A only)

    const int tid = threadIdx.x, lane = tid & 63, w = tid >> 6;
    const int nl = lane & 15, q = lane >> 4;
    const int nx = blockIdx.x, ky = blockIdx.y;
    const int n0 = nx * 64;
    const int kgbase = ky * 8;

    const int nn = n0 + w * 16 + nl;
    const float sc = scale[nn], z = zp[nn];
    const _Float16 sh = (_Float16)sc, ch = (_Float16)(-z * sc);
    const half2v s2 = {sh, sh}, c2 = {ch, ch};

    // B source (register path, r5 addressing): words t=2q,2q+1 (h0) / +8 (h1)
    const int* qb = qw + ((size_t)(nn >> 2) * K_DIM) + ((nn & 3) * 16) + 2 * q
                       + (size_t)kgbase * 64;

    const char* xp_b = (const char*)xp;

    f32x4 acc[4] = {};
    int2v qa[2][2];                          // [buf][h] — static idx (full unroll)

    // prologue: stage A(kg=0) via DMA, B(kg=0) into regs
    {
        const char* asrc = xp_b + (size_t)kgbase * 8192 + w * 2048 + lane * 16;
        __builtin_amdgcn_global_load_lds((gchar_t*)asrc,
                                         (lchar_t*)(&lds[w * 2048]), 16, 0, 0);
        __builtin_amdgcn_global_load_lds((gchar_t*)(asrc + 1024),
                                         (lchar_t*)(&lds[w * 2048 + 1024]), 16, 0, 0);
        qa[0][0] = *(const int2v*)(qb);
        qa[0][1] = *(const int2v*)(qb + 8);
    }

#pragma unroll
    for (int kg = 0; kg < 8; ++kg) {
        const int slot = kg & 1;             // compile-time (full unroll)
        // forced drain: A-DMA(kg) + B-loads(kg) complete; then barrier.
        asm volatile("s_waitcnt vmcnt(0) lgkmcnt(0)" ::: "memory");
        __builtin_amdgcn_s_barrier();
        __builtin_amdgcn_sched_barrier(0);

        // issue next step's A-DMA (other slot) + B-loads (other buf);
        // they overlap with this step's compute, drained at next barrier.
        if (kg < 7) {
            const char* asrc = xp_b + (size_t)(kgbase + kg + 1) * 8192
                             + w * 2048 + lane * 16;
            char* sb = &lds[(slot ^ 1) * 8192];
            __builtin_amdgcn_global_load_lds((gchar_t*)asrc,
                                             (lchar_t*)(sb + w * 2048), 16, 0, 0);
            __builtin_amdgcn_global_load_lds((gchar_t*)(asrc + 1024),
                                             (lchar_t*)(sb + w * 2048 + 1024), 16, 0, 0);
            qa[(kg + 1) & 1][0] = *(const int2v*)(qb + (kg + 1) * 64);
            qa[(kg + 1) & 1][1] = *(const int2v*)(qb + (kg + 1) * 64 + 8);
        }

        // compute step kg from LDS slot + reg buf
        const char* sb = &lds[slot * 8192];
#pragma unroll
        for (int h = 0; h < 2; ++h) {
            const half8 bf = build_bfrag(qa[kg & 1][h].x, qa[kg & 1][h].y, s2, c2);
#pragma unroll
            for (int mt = 0; mt < 4; ++mt) {
                const half8 af = *(const half8*)(sb + (h * 4 + mt) * 1024 + lane * 16);
                acc[mt] = __builtin_amdgcn_mfma_f32_16x16x32_f16(af, bf, acc[mt], 0, 0, 0);
            }
        }
    }

    // epilogue: each wave owns its n-subtile; no cross-wave reduce.
    f32x4* wsb = ws + ((size_t)nx * 8 + ky) * 1024;
#pragma unroll
    for (int mt = 0; mt < 4; ++mt)
        wsb[w * 256 + mt * 64 + lane] = acc[mt];
}

// ---------------- final reduce: sum 8 ky partials + bias -> out
__global__ __launch_bounds__(256) void reduce_k(
    const f32x4* __restrict__ ws,
    const float* __restrict__ bias,
    float*       __restrict__ out)
{
    const int nx = blockIdx.x, tid = threadIdx.x;
    const f32x4* wsb = ws + (size_t)nx * 8192;
#pragma unroll
    for (int ss = 0; ss < 4; ++ss) {
        const int u = tid + ss * 256;
        f32x4 v = wsb[u];
#pragma unroll
        for (int i = 1; i < 8; ++i)
            v += wsb[i * 1024 + u];
        const int w = u >> 8, mt = (u >> 6) & 3, lane = u & 63;
        const int n = nx * 64 + w * 16 + (lane & 15);
        const float bv = bias[n];
        const int m0 = mt * 16 + (lane >> 4) * 4;
#pragma unroll
        for (int r = 0; r < 4; ++r)
            out[(size_t)(m0 + r) * N_DIM + n] = v[r] + bv;
    }
}

extern "C" void kernel_launch(void* const* d_in, const int* in_sizes, int n_in,
                              void* d_out, int out_size, void* d_ws, size_t ws_size,
                              hipStream_t stream) {
    const float* x     = (const float*)d_in[0];
    const int*   qw    = (const int*)d_in[1];
    const float* scale = (const float*)d_in[2];
    const float* zp    = (const float*)d_in[3];
    const float* bias  = (const float*)d_in[4];
    float* out = (float*)d_out;

    unsigned short* xp = (unsigned short*)d_ws;                  // 512 KB
    f32x4* part_ws = (f32x4*)((char*)d_ws + (1 << 20));          // 22.5 MB partials

    prep_x<<<128, 256, 0, stream>>>(x, xp);
    dim3 grid(172, 8);
    w4_gemm<<<grid, 256, 0, stream>>>(xp, qw, scale, zp, part_ws);
    reduce_k<<<172, 256, 0, stream>>>(part_ws, bias, out);
}